// Round 13
// baseline (417.557 us; speedup 1.0000x reference)
//
#include <hip/hip_runtime.h>
#include <hip/hip_bf16.h>

typedef __attribute__((ext_vector_type(8))) short bf16x8;
typedef __attribute__((ext_vector_type(4))) float f32x4;
typedef unsigned int __attribute__((address_space(1))) as1_uint;
typedef unsigned int __attribute__((address_space(3))) as3_uint;

#define TXT 256
#define VIDN 1792
#define SEQ 2048
#define HID 3072
#define NH 48
#define HD 64
// attention scale 0.125 folded with log2(e) so softmax uses exp2 directly
#define QSCALE 0.18033688011112042f

__device__ __forceinline__ unsigned short f2bf(float f) {
  union { float f; unsigned int u; } x; x.f = f;
  unsigned int r = x.u + 0x7fffu + ((x.u >> 16) & 1u);
  return (unsigned short)(r >> 16);
}

__device__ __forceinline__ void gload16(const void* g, void* l) {
  __builtin_amdgcn_global_load_lds((const as1_uint*)g, (as3_uint*)l, 16, 0, 0);
}

// fenced raw barrier: no vmcnt drain (unlike __syncthreads), but compiler-fenced
__device__ __forceinline__ void fbar() {
  asm volatile("" ::: "memory");
  __builtin_amdgcn_s_barrier();
  asm volatile("" ::: "memory");
}

// ---------------- fp32 -> bf16 convert ----------------
__global__ __launch_bounds__(256) void cvt_kernel(const float* __restrict__ s,
                                                  unsigned short* __restrict__ d, int n) {
  int i = (blockIdx.x * 256 + threadIdx.x) * 4;
  if (i >= n) return;
  float4 v = *(const float4*)(s + i);
  ushort4 o;
  o.x = f2bf(v.x); o.y = f2bf(v.y); o.z = f2bf(v.z); o.w = f2bf(v.w);
  *(ushort4*)(d + i) = o;
}

// three HID*HID weight matrices -> contiguous bf16 dst
__global__ __launch_bounds__(256) void cvt3_kernel(const float* __restrict__ a,
                                                   const float* __restrict__ b,
                                                   const float* __restrict__ c,
                                                   unsigned short* __restrict__ d) {
  const int per = (HID * HID) / 1024;  // blocks per matrix
  int bid = blockIdx.x;
  int m = bid / per, r = bid - m * per;
  const float* s = (m == 0) ? a : (m == 1) ? b : c;
  int i = (r * 256 + threadIdx.x) * 4;
  float4 v = *(const float4*)(s + i);
  ushort4 o;
  o.x = f2bf(v.x); o.y = f2bf(v.y); o.z = f2bf(v.z); o.w = f2bf(v.w);
  *(ushort4*)(d + (size_t)m * HID * HID + i) = o;
}

// ------------- 128x128-tile deep-pipelined bf16 GEMM, C = A * Bt^T -------------
// 3-slot LDS (48 KiB -> 3 blocks/CU), 8 waves (2M x 4N, per-wave 64x32), BK=32.
//   { STAGE(t+2)=2 loads; vmcnt(4); barrier; COMPUTE(t); barrier }
// ROUND-12 PMC: SQ_LDS_BANK_CONFLICT = 21% of cycles; [row][64B] tiles are an
// 8-way conflict (16 same-slot lanes, banks repeat every 2 rows). THIS ROUND:
// T2 XOR-swizzle, rule-21-correct for global_load_lds (linear LDS dest +
// pre-swizzled GLOBAL source + swizzled ds_read):
//   byte' = byte ^ (((byte>>7)&3)<<4)   (16B-slot: lg -> lg ^ ((row>>1)&3))
// -> 16 same-slot lanes spread over 8 banks x 2 = 2-way (free, m136).
// Involution (bits 4-5 ^= bits 7-8); 16B alignment kept; same 1KB address set
// per wave (lane-permuted) so coalescing unchanged.
// launch_bounds (512,4) only: (512,6) capped allocator -> acc spill (round 10).
// MODE 0: QKV. cols<6144 -> fp32 Cq[2048][6144]; cols>=6144 -> V: +bv, bf16,
//         transposed Vt[col-6144][s]. MODE 1: +bo, fp32 out, rows vid-first.
template<int MODE>
__global__ __launch_bounds__(512, 4) void gemm256(
    const unsigned short* __restrict__ A,
    const unsigned short* __restrict__ Bt,
    int K, int ntn,
    float* __restrict__ Cq, unsigned short* __restrict__ Vt, const float* __restrict__ bv,
    float* __restrict__ Cout, const float* __restrict__ bo)
{
  __shared__ unsigned short lds[3 * 8192];  // 3 slots x (A 8KB + B 8KB) = 48 KiB
  const int tid = threadIdx.x;
  const int mt = blockIdx.x / ntn, nt = blockIdx.x % ntn;
  const int m0 = mt * 128, n0 = nt * 128;
  const int w = tid >> 6, lane = tid & 63, lr = lane & 15, lg = lane >> 4;
  const int wr = w >> 2, wc = w & 3;    // 2M x 4N wave grid; per-wave C: 64 x 32
  f32x4 acc[4][2] = {};
  const int NT = K >> 5;                // 96 K-tiles

  // staging: linear LDS dest (tid*16), pre-swizzled global source
  const int soff  = tid * 16;
  const int soffs = soff ^ (((soff >> 7) & 3) << 4);
  const int srow  = soffs >> 6;
  const int scol  = (soffs & 63) >> 1;                 // element col within BK=32
  const unsigned short* Asrc = A + (size_t)(m0 + srow) * K + scol;
  const unsigned short* Bsrc = Bt + (size_t)(n0 + srow) * K + scol;

  // swizzled ds_read element offsets (precomputed, compile-time indexed)
  int aoff[4], boff[2];
#pragma unroll
  for (int mf = 0; mf < 4; ++mf) {
    int arow = wr * 64 + mf * 16 + lr;
    aoff[mf] = arow * 32 + (lg ^ ((arow >> 1) & 3)) * 8;
  }
#pragma unroll
  for (int nf = 0; nf < 2; ++nf) {
    int brow = wc * 32 + nf * 16 + lr;
    boff[nf] = brow * 32 + (lg ^ ((brow >> 1) & 3)) * 8;
  }

#define STAGE(t)                                                               \
  {                                                                            \
    const int slot_ = (t) % 3;                                                 \
    const int k0_ = (t) << 5;                                                  \
    char* base_ = (char*)lds + slot_ * 16384;                                  \
    gload16(Asrc + k0_, base_ + soff);                                         \
    gload16(Bsrc + k0_, base_ + 8192 + soff);                                  \
  }

#define COMPUTE(t)                                                             \
  {                                                                            \
    const unsigned short* lA = lds + ((t) % 3) * 8192;                         \
    const unsigned short* lB = lA + 4096;                                      \
    bf16x8 bfr[2];                                                             \
    _Pragma("unroll")                                                          \
    for (int nf = 0; nf < 2; ++nf)                                             \
      bfr[nf] = *(const bf16x8*)&lB[boff[nf]];                                 \
    __builtin_amdgcn_s_setprio(1);                                             \
    _Pragma("unroll")                                                          \
    for (int mf = 0; mf < 4; ++mf) {                                           \
      bf16x8 af = *(const bf16x8*)&lA[aoff[mf]];                               \
      acc[mf][0] = __builtin_amdgcn_mfma_f32_16x16x32_bf16(af, bfr[0], acc[mf][0], 0, 0, 0); \
      acc[mf][1] = __builtin_amdgcn_mfma_f32_16x16x32_bf16(af, bfr[1], acc[mf][1], 0, 0, 0); \
    }                                                                          \
    __builtin_amdgcn_s_setprio(0);                                             \
  }

  STAGE(0); STAGE(1);
  int t = 0;
  for (; t < NT - 2; ++t) {
    STAGE(t + 2);
    asm volatile("s_waitcnt vmcnt(4)" ::: "memory");
    fbar();           // all waves' tile-t writes now in LDS
    COMPUTE(t);
    fbar();           // all waves done reading slot t%3 before it is re-staged
  }
  asm volatile("s_waitcnt vmcnt(2)" ::: "memory");
  fbar();
  COMPUTE(t); ++t;
  fbar();
  asm volatile("s_waitcnt vmcnt(0)" ::: "memory");
  fbar();
  COMPUTE(t);
#undef STAGE
#undef COMPUTE

  if (MODE == 0) {
    if (n0 < 6144) {
#pragma unroll
      for (int mf = 0; mf < 4; ++mf) {
        int row = m0 + wr * 64 + mf * 16 + lg * 4;
#pragma unroll
        for (int nf = 0; nf < 2; ++nf) {
          int col = n0 + wc * 32 + nf * 16 + lr;
#pragma unroll
          for (int j = 0; j < 4; ++j)
            Cq[(size_t)(row + j) * 6144 + col] = acc[mf][nf][j];
        }
      }
    } else {
#pragma unroll
      for (int mf = 0; mf < 4; ++mf) {
        int srow2 = m0 + wr * 64 + mf * 16 + lg * 4;
#pragma unroll
        for (int nf = 0; nf < 2; ++nf) {
          int n2 = n0 - 6144 + wc * 32 + nf * 16 + lr;
          float b = bv[n2];
          ushort4 pk;
          pk.x = f2bf(acc[mf][nf][0] + b);
          pk.y = f2bf(acc[mf][nf][1] + b);
          pk.z = f2bf(acc[mf][nf][2] + b);
          pk.w = f2bf(acc[mf][nf][3] + b);
          *(ushort4*)(Vt + (size_t)n2 * SEQ + srow2) = pk;
        }
      }
    }
  } else {
#pragma unroll
    for (int mf = 0; mf < 4; ++mf) {
      int row = m0 + wr * 64 + mf * 16 + lg * 4;
#pragma unroll
      for (int nf = 0; nf < 2; ++nf) {
        int col = n0 + wc * 32 + nf * 16 + lr;
        float b = bo[col];
#pragma unroll
        for (int j = 0; j < 4; ++j) {
          int s = row + j;
          int orow = (s >= TXT) ? (s - TXT) : (VIDN + s);
          Cout[(size_t)orow * HID + col] = acc[mf][nf][j] + b;
        }
      }
    }
  }
}

// ---------------- LayerNorm + head-indexed RoPE ----------------
// one wave per (s, h, qk): LN over 64 dims, rope for s>=TXT, Q scaled by QSCALE.
__global__ __launch_bounds__(256) void ln_rope_kernel(
    const float* __restrict__ QK,
    const float* __restrict__ bq, const float* __restrict__ bk,
    const float* __restrict__ gq, const float* __restrict__ bgq,
    const float* __restrict__ gk, const float* __restrict__ bgk,
    const float* __restrict__ freqs,
    unsigned short* __restrict__ Qh, unsigned short* __restrict__ Kh)
{
  int wid = blockIdx.x * 4 + (threadIdx.x >> 6);
  int lane = threadIdx.x & 63;
  int s = wid / 96;
  int rem = wid - s * 96;
  int h = rem >> 1, qk = rem & 1;
  int col = h * 64 + lane;
  float x = QK[(size_t)s * 6144 + qk * 3072 + col] + (qk ? bk[col] : bq[col]);
  float m = x;
#pragma unroll
  for (int msk = 1; msk < 64; msk <<= 1) m += __shfl_xor(m, msk);
  float mu = m * (1.0f / 64.0f);
  float xc = x - mu;
  float v = xc * xc;
#pragma unroll
  for (int msk = 1; msk < 64; msk <<= 1) v += __shfl_xor(v, msk);
  float rstd = rsqrtf(v * (1.0f / 64.0f) + 1e-5f);
  float y = xc * rstd * (qk ? gk[lane] : gq[lane]) + (qk ? bgk[lane] : bgq[lane]);
  if (s >= TXT) {
    // out[2d+j] = f[h][d][j][0]*x[2d] + f[h][d][j][1]*x[2d+1]; freqs head-indexed
    float p = __shfl_xor(y, 1);
    float xe = (lane & 1) ? p : y;
    float xo = (lane & 1) ? y : p;
    int base = h * 128 + (lane >> 1) * 4 + (lane & 1) * 2;
    y = freqs[base] * xe + freqs[base + 1] * xo;
  }
  if (!qk) y *= QSCALE;  // fold attention scale (and log2e for exp2-softmax) into Q
  (qk ? Kh : Qh)[((size_t)h * SEQ + s) * 64 + lane] = f2bf(y);
}

// ---------------- flash attention (swapped-QK^T softmax) ----------------
// grid: h * 16 q-tiles; 8 waves x 16 q-rows (QBLK=128); BKV=64; D=64.
// One K/V stage is shared by 128 q-rows: staging traffic/barriers halved vs QBLK=64.
// St = mfma(K,Q) puts q on lane&15: row-reduce = 15 in-reg ops + 2 shuffles.
__global__ __launch_bounds__(512) void fattn_kernel(
    const unsigned short* __restrict__ Qh, const unsigned short* __restrict__ Kh,
    const unsigned short* __restrict__ Vt, unsigned short* __restrict__ ctx)
{
  __shared__ unsigned short kt[2][64][32];
  __shared__ unsigned short vt[2][64][32];
  __shared__ unsigned short pl[8][16][72];
  const int h = blockIdx.x >> 4;
  const int q0 = (blockIdx.x & 15) * 128;
  const int tid = threadIdx.x, w = tid >> 6, lane = tid & 63, lr = lane & 15, lg = lane >> 4;

  bf16x8 qf0, qf1;
  {
    const unsigned short* qp = Qh + ((size_t)h * SEQ + q0 + w * 16 + lr) * 64 + lg * 8;
    qf0 = *(const bf16x8*)qp;
    qf1 = *(const bf16x8*)(qp + 32);
  }
  f32x4 oacc[4] = {};
  float mrun = -1e30f, lrun = 0.f;   // this lane's q-row = q0 + w*16 + lr

  for (int kv0 = 0; kv0 < SEQ; kv0 += 64) {
    __syncthreads();
    {
      int off = tid * 16;   // 0..8191: 512 threads cover both 4KB halves
      int half = off >> 12;
      int rem = off & 4095;
      int row = rem >> 6, cb = rem & 63;
      gload16(Kh + ((size_t)h * SEQ + kv0 + row) * 64 + half * 32 + (cb >> 1), (char*)kt + off);
      gload16(Vt + ((size_t)(h * 64 + row)) * SEQ + kv0 + half * 32 + (cb >> 1), (char*)vt + off);
    }
    __syncthreads();

    // St[kv][q]: sacc[nf][r] = S[q = lr][kv = kv0 + nf*16 + lg*4 + r]
    f32x4 sacc[4] = {};
    __builtin_amdgcn_s_setprio(1);
#pragma unroll
    for (int nf = 0; nf < 4; ++nf) {
      bf16x8 a0 = *(const bf16x8*)&kt[0][nf * 16 + lr][lg * 8];
      bf16x8 a1 = *(const bf16x8*)&kt[1][nf * 16 + lr][lg * 8];
      sacc[nf] = __builtin_amdgcn_mfma_f32_16x16x32_bf16(a0, qf0, sacc[nf], 0, 0, 0);
      sacc[nf] = __builtin_amdgcn_mfma_f32_16x16x32_bf16(a1, qf1, sacc[nf], 0, 0, 0);
    }
    __builtin_amdgcn_s_setprio(0);

    // tile max over the 16 in-register kv values, then xor16/xor32
    float mx;
    {
      float t0 = fmaxf(fmaxf(sacc[0][0], sacc[0][1]), fmaxf(sacc[0][2], sacc[0][3]));
      float t1 = fmaxf(fmaxf(sacc[1][0], sacc[1][1]), fmaxf(sacc[1][2], sacc[1][3]));
      float t2 = fmaxf(fmaxf(sacc[2][0], sacc[2][1]), fmaxf(sacc[2][2], sacc[2][3]));
      float t3 = fmaxf(fmaxf(sacc[3][0], sacc[3][1]), fmaxf(sacc[3][2], sacc[3][3]));
      mx = fmaxf(fmaxf(t0, t1), fmaxf(t2, t3));
    }
    mx = fmaxf(mx, __shfl_xor(mx, 16));
    mx = fmaxf(mx, __shfl_xor(mx, 32));

    // defer-max (log2 units): only rescale when max grew past threshold
    if (!__all(mx <= mrun + 8.0f)) {
      float mn = fmaxf(mrun, mx);
      float corr = exp2f(mrun - mn);
      lrun *= corr;
      mrun = mn;
      float c0 = __shfl(corr, lg * 4 + 0);
      float c1 = __shfl(corr, lg * 4 + 1);
      float c2 = __shfl(corr, lg * 4 + 2);
      float c3 = __shfl(corr, lg * 4 + 3);
#pragma unroll
      for (int df = 0; df < 4; ++df) {
        oacc[df][0] *= c0; oacc[df][1] *= c1;
        oacc[df][2] *= c2; oacc[df][3] *= c3;
      }
    }

    // P = exp2(S - mrun); row-sum; pack to bf16 and write P[q][kv] as b64
    float pr[4][4];
#pragma unroll
    for (int nf = 0; nf < 4; ++nf)
#pragma unroll
      for (int r = 0; r < 4; ++r)
        pr[nf][r] = exp2f(sacc[nf][r] - mrun);
    float rs;
    {
      float s0 = (pr[0][0] + pr[0][1]) + (pr[0][2] + pr[0][3]);
      float s1 = (pr[1][0] + pr[1][1]) + (pr[1][2] + pr[1][3]);
      float s2 = (pr[2][0] + pr[2][1]) + (pr[2][2] + pr[2][3]);
      float s3 = (pr[3][0] + pr[3][1]) + (pr[3][2] + pr[3][3]);
      rs = (s0 + s1) + (s2 + s3);
    }
    rs += __shfl_xor(rs, 16);
    rs += __shfl_xor(rs, 32);
    lrun += rs;

#pragma unroll
    for (int nf = 0; nf < 4; ++nf) {
      union { __hip_bfloat162 h; unsigned int u; } c0, c1;
      c0.h = __float22bfloat162_rn(make_float2(pr[nf][0], pr[nf][1]));
      c1.h = __float22bfloat162_rn(make_float2(pr[nf][2], pr[nf][3]));
      uint2 pw; pw.x = c0.u; pw.y = c1.u;
      *(uint2*)&pl[w][lr][nf * 16 + lg * 4] = pw;
    }
    // no barrier: pl slice is per-wave; lgkmcnt orders write->read

    bf16x8 pa0 = *(const bf16x8*)&pl[w][lr][lg * 8];
    bf16x8 pa1 = *(const bf16x8*)&pl[w][lr][32 + lg * 8];
    __builtin_amdgcn_s_setprio(1);
#pragma unroll
    for (int df = 0; df < 4; ++df) {
      bf16x8 v0 = *(const bf16x8*)&vt[0][df * 16 + lr][lg * 8];
      bf16x8 v1 = *(const bf16x8*)&vt[1][df * 16 + lr][lg * 8];
      oacc[df] = __builtin_amdgcn_mfma_f32_16x16x32_bf16(pa0, v0, oacc[df], 0, 0, 0);
      oacc[df] = __builtin_amdgcn_mfma_f32_16x16x32_bf16(pa1, v1, oacc[df], 0, 0, 0);
    }
    __builtin_amdgcn_s_setprio(0);
  }

  // epilogue: move 1/lrun (at q=lane&15 layout) to C-layout rows via shfl
  float linv = 1.0f / lrun;
  float i0 = __shfl(linv, lg * 4 + 0);
  float i1 = __shfl(linv, lg * 4 + 1);
  float i2 = __shfl(linv, lg * 4 + 2);
  float i3 = __shfl(linv, lg * 4 + 3);
#pragma unroll
  for (int df = 0; df < 4; ++df) {
    int s = q0 + w * 16 + lg * 4;
    int dcol = h * 64 + df * 16 + lr;
    ctx[(size_t)(s + 0) * HID + dcol] = f2bf(oacc[df][0] * i0);
    ctx[(size_t)(s + 1) * HID + dcol] = f2bf(oacc[df][1] * i1);
    ctx[(size_t)(s + 2) * HID + dcol] = f2bf(oacc[df][2] * i2);
    ctx[(size_t)(s + 3) * HID + dcol] = f2bf(oacc[df][3] * i3);
  }
}

extern "C" void kernel_launch(void* const* d_in, const int* in_sizes, int n_in,
                              void* d_out, int out_size, void* d_ws, size_t ws_size,
                              hipStream_t stream) {
  const float* combined = (const float*)d_in[0];
  const float* freqs    = (const float*)d_in[1];
  const float* Wq  = (const float*)d_in[2];
  const float* bq  = (const float*)d_in[3];
  const float* Wk  = (const float*)d_in[4];
  const float* bk  = (const float*)d_in[5];
  const float* Wv  = (const float*)d_in[6];
  const float* bv  = (const float*)d_in[7];
  const float* Wo  = (const float*)d_in[8];
  const float* bo  = (const float*)d_in[9];
  const float* gq  = (const float*)d_in[10];
  const float* bgq = (const float*)d_in[11];
  const float* gk  = (const float*)d_in[12];
  const float* bgk = (const float*)d_in[13];
  float* out = (float*)d_out;  // reference output dtype is float32

  char* ws = (char*)d_ws;
  unsigned short* Abf  = (unsigned short*)ws; ws += (size_t)SEQ * HID * 2;    // reused as ctx
  unsigned short* Wqkv = (unsigned short*)ws; ws += (size_t)3 * HID * HID * 2;
  float*          QK   = (float*)ws;          ws += (size_t)SEQ * 6144 * 4;   // reused for Wob
  unsigned short* Qh   = (unsigned short*)ws; ws += (size_t)NH * SEQ * HD * 2;
  unsigned short* Kh   = (unsigned short*)ws; ws += (size_t)NH * SEQ * HD * 2;
  unsigned short* Vt   = (unsigned short*)ws; ws += (size_t)NH * HD * SEQ * 2;
  unsigned short* Wob  = (unsigned short*)QK;   // alias: QK dead after ln_rope
  unsigned short* ctx  = Abf;                   // alias: Abf dead after QKV GEMM

  cvt_kernel<<<(SEQ * HID) / 1024, 256, 0, stream>>>(combined, Abf, SEQ * HID);
  cvt3_kernel<<<3 * (HID * HID) / 1024, 256, 0, stream>>>(Wq, Wk, Wv, Wqkv);

  // QKV GEMM: M=2048, N=9216, K=3072 -> 16x72 = 1152 blocks of 128x128, 3/CU
  gemm256<0><<<16 * 72, 512, 0, stream>>>(Abf, Wqkv, HID, 72, QK, Vt, bv, nullptr, nullptr);

  // LN + rope: 2048*48*2 waves
  ln_rope_kernel<<<(SEQ * NH * 2) / 4, 256, 0, stream>>>(QK, bq, bk, gq, bgq, gk, bgk, freqs, Qh, Kh);

  // Wo -> bf16 into the (now dead) QK region
  cvt_kernel<<<(HID * HID) / 1024, 256, 0, stream>>>(Wo, Wob, HID * HID);

  // flash attention: 48 heads x 16 q-tiles of 128 rows, 512 threads
  fattn_kernel<<<NH * 16, 512, 0, stream>>>(Qh, Kh, Vt, ctx);

  // final GEMM: M=2048, N=3072, K=3072 -> 16x24 = 384 blocks of 128x128
  gemm256<1><<<16 * 24, 512, 0, stream>>>(ctx, Wob, HID, 24, nullptr, nullptr, nullptr, out, bo);
}

// Round 14
// 404.179 us; speedup vs baseline: 1.0331x; 1.0331x over previous
//
#include <hip/hip_runtime.h>
#include <hip/hip_bf16.h>

typedef __attribute__((ext_vector_type(8))) short bf16x8;
typedef __attribute__((ext_vector_type(4))) float f32x4;
typedef unsigned int __attribute__((address_space(1))) as1_uint;
typedef unsigned int __attribute__((address_space(3))) as3_uint;

#define TXT 256
#define VIDN 1792
#define SEQ 2048
#define HID 3072
#define NH 48
#define HD 64
// attention scale 0.125 folded with log2(e) so softmax uses exp2 directly
#define QSCALE 0.18033688011112042f

__device__ __forceinline__ unsigned short f2bf(float f) {
  union { float f; unsigned int u; } x; x.f = f;
  unsigned int r = x.u + 0x7fffu + ((x.u >> 16) & 1u);
  return (unsigned short)(r >> 16);
}

__device__ __forceinline__ void gload16(const void* g, void* l) {
  __builtin_amdgcn_global_load_lds((const as1_uint*)g, (as3_uint*)l, 16, 0, 0);
}

// fenced raw barrier: no vmcnt drain (unlike __syncthreads), but compiler-fenced
__device__ __forceinline__ void fbar() {
  asm volatile("" ::: "memory");
  __builtin_amdgcn_s_barrier();
  asm volatile("" ::: "memory");
}

// ---------------- fp32 -> bf16 convert ----------------
__global__ __launch_bounds__(256) void cvt_kernel(const float* __restrict__ s,
                                                  unsigned short* __restrict__ d, int n) {
  int i = (blockIdx.x * 256 + threadIdx.x) * 4;
  if (i >= n) return;
  float4 v = *(const float4*)(s + i);
  ushort4 o;
  o.x = f2bf(v.x); o.y = f2bf(v.y); o.z = f2bf(v.z); o.w = f2bf(v.w);
  *(ushort4*)(d + i) = o;
}

// three HID*HID weight matrices -> contiguous bf16 dst
__global__ __launch_bounds__(256) void cvt3_kernel(const float* __restrict__ a,
                                                   const float* __restrict__ b,
                                                   const float* __restrict__ c,
                                                   unsigned short* __restrict__ d) {
  const int per = (HID * HID) / 1024;  // blocks per matrix
  int bid = blockIdx.x;
  int m = bid / per, r = bid - m * per;
  const float* s = (m == 0) ? a : (m == 1) ? b : c;
  int i = (r * 256 + threadIdx.x) * 4;
  float4 v = *(const float4*)(s + i);
  ushort4 o;
  o.x = f2bf(v.x); o.y = f2bf(v.y); o.z = f2bf(v.z); o.w = f2bf(v.w);
  *(ushort4*)(d + (size_t)m * HID * HID + i) = o;
}

// ------------- 128x128-tile deep-pipelined bf16 GEMM, C = A * Bt^T -------------
// ROUND-13 PMC: swizzle zeroed SQ_LDS_BANK_CONFLICT (2.1e7 -> 0) but time flat
// -> LDS BANDWIDTH bound: 8 waves x 64x32/wave = 6KB ds_read per 131K FLOP.
// THIS ROUND: 4 waves (256 thr) x 64x64/wave: 8KB ds_read per 262K FLOP (2x
// FLOP/LDS-byte; LDS cap 43%->57% MfmaUtil). Same 3-slot/depth-2/swizzle
// template, staging now 4 gloads/thread -> vmcnt(8)/(4)/(0).
//   { STAGE(t+2)=4 loads; vmcnt(8); barrier; COMPUTE(t); barrier }
// RAW: vmcnt(8) = tiles t+1,t+2 in flight, tile t drained pre-barrier.
// WAR: STAGE(t+2) overwrites slot (t-1)%3, readers passed prev trailing barrier.
// Swizzle (rule-21): linear LDS dest + pre-swizzled GLOBAL src + swizzled
// ds_read, byte' = byte ^ (((byte>>7)&3)<<4).
// launch_bounds (256,4): cap 128 VGPR (round-10: tighter caps spill acc).
// MODE 0: QKV. cols<6144 -> fp32 Cq[2048][6144]; cols>=6144 -> V: +bv, bf16,
//         transposed Vt[col-6144][s]. MODE 1: +bo, fp32 out, rows vid-first.
template<int MODE>
__global__ __launch_bounds__(256, 4) void gemm256(
    const unsigned short* __restrict__ A,
    const unsigned short* __restrict__ Bt,
    int K, int ntn,
    float* __restrict__ Cq, unsigned short* __restrict__ Vt, const float* __restrict__ bv,
    float* __restrict__ Cout, const float* __restrict__ bo)
{
  __shared__ unsigned short lds[3 * 8192];  // 3 slots x (A 8KB + B 8KB) = 48 KiB
  const int tid = threadIdx.x;
  const int mt = blockIdx.x / ntn, nt = blockIdx.x % ntn;
  const int m0 = mt * 128, n0 = nt * 128;
  const int w = tid >> 6, lane = tid & 63, lr = lane & 15, lg = lane >> 4;
  const int wr = w >> 1, wc = w & 1;    // 2M x 2N wave grid; per-wave C: 64 x 64
  f32x4 acc[4][4] = {};
  const int NT = K >> 5;                // 96 K-tiles

  // staging: linear LDS dest, pre-swizzled global source (2 chunks per matrix)
  const unsigned short* Asrc[2];
  const unsigned short* Bsrc[2];
  int soffl[2];
#pragma unroll
  for (int c = 0; c < 2; ++c) {
    int so = (c * 256 + tid) * 16;
    soffl[c] = so;
    int ss = so ^ (((so >> 7) & 3) << 4);
    int sr = ss >> 6, sc = (ss & 63) >> 1;
    Asrc[c] = A + (size_t)(m0 + sr) * K + sc;
    Bsrc[c] = Bt + (size_t)(n0 + sr) * K + sc;
  }

  // swizzled ds_read element offsets (precomputed, compile-time indexed)
  int aoff[4], boff[4];
#pragma unroll
  for (int mf = 0; mf < 4; ++mf) {
    int arow = wr * 64 + mf * 16 + lr;
    aoff[mf] = arow * 32 + (lg ^ ((arow >> 1) & 3)) * 8;
  }
#pragma unroll
  for (int nf = 0; nf < 4; ++nf) {
    int brow = wc * 64 + nf * 16 + lr;
    boff[nf] = brow * 32 + (lg ^ ((brow >> 1) & 3)) * 8;
  }

#define STAGE(t)                                                               \
  {                                                                            \
    const int slot_ = (t) % 3;                                                 \
    const int k0_ = (t) << 5;                                                  \
    char* base_ = (char*)lds + slot_ * 16384;                                  \
    _Pragma("unroll")                                                          \
    for (int c = 0; c < 2; ++c) {                                              \
      gload16(Asrc[c] + k0_, base_ + soffl[c]);                                \
      gload16(Bsrc[c] + k0_, base_ + 8192 + soffl[c]);                         \
    }                                                                          \
  }

#define COMPUTE(t)                                                             \
  {                                                                            \
    const unsigned short* lA = lds + ((t) % 3) * 8192;                         \
    const unsigned short* lB = lA + 4096;                                      \
    bf16x8 bfr[4];                                                             \
    _Pragma("unroll")                                                          \
    for (int nf = 0; nf < 4; ++nf)                                             \
      bfr[nf] = *(const bf16x8*)&lB[boff[nf]];                                 \
    __builtin_amdgcn_s_setprio(1);                                             \
    _Pragma("unroll")                                                          \
    for (int mf = 0; mf < 4; ++mf) {                                           \
      bf16x8 af = *(const bf16x8*)&lA[aoff[mf]];                               \
      acc[mf][0] = __builtin_amdgcn_mfma_f32_16x16x32_bf16(af, bfr[0], acc[mf][0], 0, 0, 0); \
      acc[mf][1] = __builtin_amdgcn_mfma_f32_16x16x32_bf16(af, bfr[1], acc[mf][1], 0, 0, 0); \
      acc[mf][2] = __builtin_amdgcn_mfma_f32_16x16x32_bf16(af, bfr[2], acc[mf][2], 0, 0, 0); \
      acc[mf][3] = __builtin_amdgcn_mfma_f32_16x16x32_bf16(af, bfr[3], acc[mf][3], 0, 0, 0); \
    }                                                                          \
    __builtin_amdgcn_s_setprio(0);                                             \
  }

  STAGE(0); STAGE(1);
  int t = 0;
  for (; t < NT - 2; ++t) {
    STAGE(t + 2);
    asm volatile("s_waitcnt vmcnt(8)" ::: "memory");
    fbar();           // all waves' tile-t writes now in LDS
    COMPUTE(t);
    fbar();           // all waves done reading slot t%3 before it is re-staged
  }
  asm volatile("s_waitcnt vmcnt(4)" ::: "memory");
  fbar();
  COMPUTE(t); ++t;
  fbar();
  asm volatile("s_waitcnt vmcnt(0)" ::: "memory");
  fbar();
  COMPUTE(t);
#undef STAGE
#undef COMPUTE

  if (MODE == 0) {
    if (n0 < 6144) {
#pragma unroll
      for (int mf = 0; mf < 4; ++mf) {
        int row = m0 + wr * 64 + mf * 16 + lg * 4;
#pragma unroll
        for (int nf = 0; nf < 4; ++nf) {
          int col = n0 + wc * 64 + nf * 16 + lr;
#pragma unroll
          for (int j = 0; j < 4; ++j)
            Cq[(size_t)(row + j) * 6144 + col] = acc[mf][nf][j];
        }
      }
    } else {
#pragma unroll
      for (int mf = 0; mf < 4; ++mf) {
        int srow2 = m0 + wr * 64 + mf * 16 + lg * 4;
#pragma unroll
        for (int nf = 0; nf < 4; ++nf) {
          int n2 = n0 - 6144 + wc * 64 + nf * 16 + lr;
          float b = bv[n2];
          ushort4 pk;
          pk.x = f2bf(acc[mf][nf][0] + b);
          pk.y = f2bf(acc[mf][nf][1] + b);
          pk.z = f2bf(acc[mf][nf][2] + b);
          pk.w = f2bf(acc[mf][nf][3] + b);
          *(ushort4*)(Vt + (size_t)n2 * SEQ + srow2) = pk;
        }
      }
    }
  } else {
#pragma unroll
    for (int mf = 0; mf < 4; ++mf) {
      int row = m0 + wr * 64 + mf * 16 + lg * 4;
#pragma unroll
      for (int nf = 0; nf < 4; ++nf) {
        int col = n0 + wc * 64 + nf * 16 + lr;
        float b = bo[col];
#pragma unroll
        for (int j = 0; j < 4; ++j) {
          int s = row + j;
          int orow = (s >= TXT) ? (s - TXT) : (VIDN + s);
          Cout[(size_t)orow * HID + col] = acc[mf][nf][j] + b;
        }
      }
    }
  }
}

// ---------------- LayerNorm + head-indexed RoPE ----------------
// one wave per (s, h, qk): LN over 64 dims, rope for s>=TXT, Q scaled by QSCALE.
__global__ __launch_bounds__(256) void ln_rope_kernel(
    const float* __restrict__ QK,
    const float* __restrict__ bq, const float* __restrict__ bk,
    const float* __restrict__ gq, const float* __restrict__ bgq,
    const float* __restrict__ gk, const float* __restrict__ bgk,
    const float* __restrict__ freqs,
    unsigned short* __restrict__ Qh, unsigned short* __restrict__ Kh)
{
  int wid = blockIdx.x * 4 + (threadIdx.x >> 6);
  int lane = threadIdx.x & 63;
  int s = wid / 96;
  int rem = wid - s * 96;
  int h = rem >> 1, qk = rem & 1;
  int col = h * 64 + lane;
  float x = QK[(size_t)s * 6144 + qk * 3072 + col] + (qk ? bk[col] : bq[col]);
  float m = x;
#pragma unroll
  for (int msk = 1; msk < 64; msk <<= 1) m += __shfl_xor(m, msk);
  float mu = m * (1.0f / 64.0f);
  float xc = x - mu;
  float v = xc * xc;
#pragma unroll
  for (int msk = 1; msk < 64; msk <<= 1) v += __shfl_xor(v, msk);
  float rstd = rsqrtf(v * (1.0f / 64.0f) + 1e-5f);
  float y = xc * rstd * (qk ? gk[lane] : gq[lane]) + (qk ? bgk[lane] : bgq[lane]);
  if (s >= TXT) {
    // out[2d+j] = f[h][d][j][0]*x[2d] + f[h][d][j][1]*x[2d+1]; freqs head-indexed
    float p = __shfl_xor(y, 1);
    float xe = (lane & 1) ? p : y;
    float xo = (lane & 1) ? y : p;
    int base = h * 128 + (lane >> 1) * 4 + (lane & 1) * 2;
    y = freqs[base] * xe + freqs[base + 1] * xo;
  }
  if (!qk) y *= QSCALE;  // fold attention scale (and log2e for exp2-softmax) into Q
  (qk ? Kh : Qh)[((size_t)h * SEQ + s) * 64 + lane] = f2bf(y);
}

// ---------------- flash attention (swapped-QK^T softmax) ----------------
// grid: h * 16 q-tiles; 8 waves x 16 q-rows (QBLK=128); BKV=64; D=64.
// ROUND-14: double-buffered K/V staging with counted vmcnt (same proven
// template as the GEMM): { FSTAGE(t+1)=2 gloads; vmcnt(2); fbar; compute(t);
// fbar } — staging latency hides under previous iter's compute instead of
// being drained by __syncthreads. Q-loads issue BEFORE FSTAGE(0): FIFO vmcnt
// ordering means vmcnt(2) also covers them.
// St = mfma(K,Q) puts q on lane&15: row-reduce = 15 in-reg ops + 2 shuffles.
__global__ __launch_bounds__(512) void fattn_kernel(
    const unsigned short* __restrict__ Qh, const unsigned short* __restrict__ Kh,
    const unsigned short* __restrict__ Vt, unsigned short* __restrict__ ctx)
{
  __shared__ unsigned short kt[2][2][64][32];  // [slot][half][row][col]
  __shared__ unsigned short vt[2][2][64][32];
  __shared__ unsigned short pl[8][16][72];
  const int h = blockIdx.x >> 4;
  const int q0 = (blockIdx.x & 15) * 128;
  const int tid = threadIdx.x, w = tid >> 6, lane = tid & 63, lr = lane & 15, lg = lane >> 4;

  bf16x8 qf0, qf1;
  {
    const unsigned short* qp = Qh + ((size_t)h * SEQ + q0 + w * 16 + lr) * 64 + lg * 8;
    qf0 = *(const bf16x8*)qp;
    qf1 = *(const bf16x8*)(qp + 32);
  }
  f32x4 oacc[4] = {};
  float mrun = -1e30f, lrun = 0.f;   // this lane's q-row = q0 + w*16 + lr

  // per-thread staging addresses (fixed row/half/col; kv advances the source)
  const int soff = tid * 16;
  const int shalf = soff >> 12;
  const int srem = soff & 4095;
  const int srow = srem >> 6, scb = srem & 63;
  const unsigned short* Ksrc = Kh + ((size_t)h * SEQ + srow) * 64 + shalf * 32 + (scb >> 1);
  const unsigned short* Vsrc = Vt + ((size_t)(h * 64 + srow)) * SEQ + shalf * 32 + (scb >> 1);

#define FSTAGE(t)                                                              \
  {                                                                            \
    const int sl_ = (t) & 1;                                                   \
    const int kv0_ = (t) << 6;                                                 \
    gload16(Ksrc + (size_t)kv0_ * 64, (char*)kt + sl_ * 8192 + soff);          \
    gload16(Vsrc + kv0_, (char*)vt + sl_ * 8192 + soff);                       \
  }

  FSTAGE(0);
  for (int t = 0; t < 32; ++t) {
    const int sl = t & 1;
    if (t < 31) {
      FSTAGE(t + 1);
      asm volatile("s_waitcnt vmcnt(2)" ::: "memory");
    } else {
      asm volatile("s_waitcnt vmcnt(0)" ::: "memory");
    }
    fbar();   // all waves' tile-t K/V writes now in LDS

    // St[kv][q]: sacc[nf][r] = S[q = lr][kv = t*64 + nf*16 + lg*4 + r]
    f32x4 sacc[4] = {};
    __builtin_amdgcn_s_setprio(1);
#pragma unroll
    for (int nf = 0; nf < 4; ++nf) {
      bf16x8 a0 = *(const bf16x8*)&kt[sl][0][nf * 16 + lr][lg * 8];
      bf16x8 a1 = *(const bf16x8*)&kt[sl][1][nf * 16 + lr][lg * 8];
      sacc[nf] = __builtin_amdgcn_mfma_f32_16x16x32_bf16(a0, qf0, sacc[nf], 0, 0, 0);
      sacc[nf] = __builtin_amdgcn_mfma_f32_16x16x32_bf16(a1, qf1, sacc[nf], 0, 0, 0);
    }
    __builtin_amdgcn_s_setprio(0);

    // tile max over the 16 in-register kv values, then xor16/xor32
    float mx;
    {
      float t0 = fmaxf(fmaxf(sacc[0][0], sacc[0][1]), fmaxf(sacc[0][2], sacc[0][3]));
      float t1 = fmaxf(fmaxf(sacc[1][0], sacc[1][1]), fmaxf(sacc[1][2], sacc[1][3]));
      float t2 = fmaxf(fmaxf(sacc[2][0], sacc[2][1]), fmaxf(sacc[2][2], sacc[2][3]));
      float t3 = fmaxf(fmaxf(sacc[3][0], sacc[3][1]), fmaxf(sacc[3][2], sacc[3][3]));
      mx = fmaxf(fmaxf(t0, t1), fmaxf(t2, t3));
    }
    mx = fmaxf(mx, __shfl_xor(mx, 16));
    mx = fmaxf(mx, __shfl_xor(mx, 32));

    // defer-max (log2 units): only rescale when max grew past threshold
    if (!__all(mx <= mrun + 8.0f)) {
      float mn = fmaxf(mrun, mx);
      float corr = exp2f(mrun - mn);
      lrun *= corr;
      mrun = mn;
      float c0 = __shfl(corr, lg * 4 + 0);
      float c1 = __shfl(corr, lg * 4 + 1);
      float c2 = __shfl(corr, lg * 4 + 2);
      float c3 = __shfl(corr, lg * 4 + 3);
#pragma unroll
      for (int df = 0; df < 4; ++df) {
        oacc[df][0] *= c0; oacc[df][1] *= c1;
        oacc[df][2] *= c2; oacc[df][3] *= c3;
      }
    }

    // P = exp2(S - mrun); row-sum; pack to bf16 and write P[q][kv] as b64
    float pr[4][4];
#pragma unroll
    for (int nf = 0; nf < 4; ++nf)
#pragma unroll
      for (int r = 0; r < 4; ++r)
        pr[nf][r] = exp2f(sacc[nf][r] - mrun);
    float rs;
    {
      float s0 = (pr[0][0] + pr[0][1]) + (pr[0][2] + pr[0][3]);
      float s1 = (pr[1][0] + pr[1][1]) + (pr[1][2] + pr[1][3]);
      float s2 = (pr[2][0] + pr[2][1]) + (pr[2][2] + pr[2][3]);
      float s3 = (pr[3][0] + pr[3][1]) + (pr[3][2] + pr[3][3]);
      rs = (s0 + s1) + (s2 + s3);
    }
    rs += __shfl_xor(rs, 16);
    rs += __shfl_xor(rs, 32);
    lrun += rs;

#pragma unroll
    for (int nf = 0; nf < 4; ++nf) {
      union { __hip_bfloat162 h; unsigned int u; } c0, c1;
      c0.h = __float22bfloat162_rn(make_float2(pr[nf][0], pr[nf][1]));
      c1.h = __float22bfloat162_rn(make_float2(pr[nf][2], pr[nf][3]));
      uint2 pw; pw.x = c0.u; pw.y = c1.u;
      *(uint2*)&pl[w][lr][nf * 16 + lg * 4] = pw;
    }
    // no barrier: pl slice is per-wave; lgkmcnt orders write->read

    bf16x8 pa0 = *(const bf16x8*)&pl[w][lr][lg * 8];
    bf16x8 pa1 = *(const bf16x8*)&pl[w][lr][32 + lg * 8];
    __builtin_amdgcn_s_setprio(1);
#pragma unroll
    for (int df = 0; df < 4; ++df) {
      bf16x8 v0 = *(const bf16x8*)&vt[sl][0][df * 16 + lr][lg * 8];
      bf16x8 v1 = *(const bf16x8*)&vt[sl][1][df * 16 + lr][lg * 8];
      oacc[df] = __builtin_amdgcn_mfma_f32_16x16x32_bf16(pa0, v0, oacc[df], 0, 0, 0);
      oacc[df] = __builtin_amdgcn_mfma_f32_16x16x32_bf16(pa1, v1, oacc[df], 0, 0, 0);
    }
    __builtin_amdgcn_s_setprio(0);

    fbar();   // all waves done reading slot sl before it is re-staged
  }
#undef FSTAGE

  // epilogue: move 1/lrun (at q=lane&15 layout) to C-layout rows via shfl
  float linv = 1.0f / lrun;
  float i0 = __shfl(linv, lg * 4 + 0);
  float i1 = __shfl(linv, lg * 4 + 1);
  float i2 = __shfl(linv, lg * 4 + 2);
  float i3 = __shfl(linv, lg * 4 + 3);
#pragma unroll
  for (int df = 0; df < 4; ++df) {
    int s = q0 + w * 16 + lg * 4;
    int dcol = h * 64 + df * 16 + lr;
    ctx[(size_t)(s + 0) * HID + dcol] = f2bf(oacc[df][0] * i0);
    ctx[(size_t)(s + 1) * HID + dcol] = f2bf(oacc[df][1] * i1);
    ctx[(size_t)(s + 2) * HID + dcol] = f2bf(oacc[df][2] * i2);
    ctx[(size_t)(s + 3) * HID + dcol] = f2bf(oacc[df][3] * i3);
  }
}

extern "C" void kernel_launch(void* const* d_in, const int* in_sizes, int n_in,
                              void* d_out, int out_size, void* d_ws, size_t ws_size,
                              hipStream_t stream) {
  const float* combined = (const float*)d_in[0];
  const float* freqs    = (const float*)d_in[1];
  const float* Wq  = (const float*)d_in[2];
  const float* bq  = (const float*)d_in[3];
  const float* Wk  = (const float*)d_in[4];
  const float* bk  = (const float*)d_in[5];
  const float* Wv  = (const float*)d_in[6];
  const float* bv  = (const float*)d_in[7];
  const float* Wo  = (const float*)d_in[8];
  const float* bo  = (const float*)d_in[9];
  const float* gq  = (const float*)d_in[10];
  const float* bgq = (const float*)d_in[11];
  const float* gk  = (const float*)d_in[12];
  const float* bgk = (const float*)d_in[13];
  float* out = (float*)d_out;  // reference output dtype is float32

  char* ws = (char*)d_ws;
  unsigned short* Abf  = (unsigned short*)ws; ws += (size_t)SEQ * HID * 2;    // reused as ctx
  unsigned short* Wqkv = (unsigned short*)ws; ws += (size_t)3 * HID * HID * 2;
  float*          QK   = (float*)ws;          ws += (size_t)SEQ * 6144 * 4;   // reused for Wob
  unsigned short* Qh   = (unsigned short*)ws; ws += (size_t)NH * SEQ * HD * 2;
  unsigned short* Kh   = (unsigned short*)ws; ws += (size_t)NH * SEQ * HD * 2;
  unsigned short* Vt   = (unsigned short*)ws; ws += (size_t)NH * HD * SEQ * 2;
  unsigned short* Wob  = (unsigned short*)QK;   // alias: QK dead after ln_rope
  unsigned short* ctx  = Abf;                   // alias: Abf dead after QKV GEMM

  cvt_kernel<<<(SEQ * HID) / 1024, 256, 0, stream>>>(combined, Abf, SEQ * HID);
  cvt3_kernel<<<3 * (HID * HID) / 1024, 256, 0, stream>>>(Wq, Wk, Wv, Wqkv);

  // QKV GEMM: M=2048, N=9216, K=3072 -> 16x72 = 1152 blocks of 128x128, 3/CU
  gemm256<0><<<16 * 72, 256, 0, stream>>>(Abf, Wqkv, HID, 72, QK, Vt, bv, nullptr, nullptr);

  // LN + rope: 2048*48*2 waves
  ln_rope_kernel<<<(SEQ * NH * 2) / 4, 256, 0, stream>>>(QK, bq, bk, gq, bgq, gk, bgk, freqs, Qh, Kh);

  // Wo -> bf16 into the (now dead) QK region
  cvt_kernel<<<(HID * HID) / 1024, 256, 0, stream>>>(Wo, Wob, HID * HID);

  // flash attention: 48 heads x 16 q-tiles of 128 rows, 512 threads
  fattn_kernel<<<NH * 16, 512, 0, stream>>>(Qh, Kh, Vt, ctx);

  // final GEMM: M=2048, N=3072, K=3072 -> 16x24 = 384 blocks of 128x128
  gemm256<1><<<16 * 24, 256, 0, stream>>>(ctx, Wob, HID, 24, nullptr, nullptr, nullptr, out, bo);
}